// Round 4
// baseline (316.780 us; speedup 1.0000x reference)
//
#include <hip/hip_runtime.h>

#define DIM   256
#define DH    64
#define NKS   64      // K_SLOTS
#define NH    4       // HEADS
#define SEQ   32768
#define NCOPY 4       // replicated global accumulators (atomic churn /4)

typedef float f32x4  __attribute__((ext_vector_type(4)));
typedef short bf16x8 __attribute__((ext_vector_type(8)));

__device__ __forceinline__ unsigned short f2bf(float f) {
    union { float f; unsigned int u; } v; v.f = f;
    return (unsigned short)((v.u + 0x7FFFu + ((v.u >> 16) & 1u)) >> 16);  // RNE
}

// ---------------- K0: Q = LN(mu) @ Wq + bq  -> Q[64][256] fp32 ----------------
__global__ void k_q(const float* __restrict__ mu, const float* __restrict__ g,
                    const float* __restrict__ bb, const float* __restrict__ Wq,
                    const float* __restrict__ bq, float* __restrict__ Q) {
    __shared__ float nrm[DIM];
    __shared__ float red1[4], red2[4];
    const int k = blockIdx.x, t = threadIdx.x;
    float x = mu[k * DIM + t];
    float s = x;
    #pragma unroll
    for (int o = 1; o <= 32; o <<= 1) s += __shfl_xor(s, o);
    if ((t & 63) == 0) red1[t >> 6] = s;
    __syncthreads();
    const float mean = (red1[0] + red1[1] + red1[2] + red1[3]) * (1.0f / DIM);
    const float d = x - mean;
    float vs = d * d;
    #pragma unroll
    for (int o = 1; o <= 32; o <<= 1) vs += __shfl_xor(vs, o);
    if ((t & 63) == 0) red2[t >> 6] = vs;
    __syncthreads();
    const float var = (red2[0] + red2[1] + red2[2] + red2[3]) * (1.0f / DIM);
    nrm[t] = d * rsqrtf(var + 1e-5f) * g[t] + bb[t];
    __syncthreads();
    float acc = bq[t];
    for (int c = 0; c < DIM; ++c) acc += nrm[c] * Wq[c * DIM + t];
    Q[k * DIM + t] = acc;
}

// ---- K1: fold scores matrix + transpose. W2T[n][c] (bf16, c contiguous) ----
__global__ void k_fold(const float* __restrict__ Q, const float* __restrict__ Wk,
                       const float* __restrict__ bk, const float* __restrict__ Wv,
                       const float* __restrict__ bv,
                       unsigned short* __restrict__ W2T, float* __restrict__ b2) {
    const int n = blockIdx.x, t = threadIdx.x;
    __shared__ float q[DH];
    if (n < 256) {
        const int h = n >> 6, k = n & 63;
        if (t < DH) q[t] = Q[k * DIM + h * DH + t];
        __syncthreads();
        float acc = 0.f;
        #pragma unroll 8
        for (int d0 = 0; d0 < DH; ++d0) acc += Wk[t * DIM + h * DH + d0] * q[d0];
        W2T[n * 256 + t] = f2bf(acc * 0.125f);
        if (t == 0) {
            float ba = 0.f;
            for (int d0 = 0; d0 < DH; ++d0) ba += bk[h * DH + d0] * q[d0];
            b2[n] = ba * 0.125f;
        }
    } else {
        const int col = n - 256;
        W2T[n * 256 + t] = f2bf(Wv[t * DIM + col]);
        if (t == 0) b2[n] = bv[col];
    }
}

// ---------------- K2: fused main kernel, 16-wave blocks ----------------
// Grid 256 = 4b x 64chunks (512 rows each = 8 tiles of 64). 1024 thr = 16 waves.
// Occupancy design: per-SIMD reg pool = 512; target 4 waves/SIMD -> <=128
// regs/lane TOTAL (VGPR+AGPR unified on gfx950). acc32 + pv16 + pf16 + pk16
// + misc ~= 110. __launch_bounds__(1024,4) enforces it.
// Dynamic LDS 128 KiB: Xbuf0 @0 (32K), Xbuf1 @32768, A @65536 (32K:
// [4h][64k][64s] bf16 swz), V @98304 (32K: [256d][64s] bf16 swz).
// Wave roles: w<8: scores (h=w&3, s-half=w>>2), w>=8: V cols (dg, s-half).
// PV: all 16 waves, (head=w>>2, d-16th=w&3), pv[4] = 16 regs.
// Per tile: [A] prefetch X(t+1) -> pf; [B] Y-GEMM (C-init = bias);
// [C] softmax / V-pack -> pk; [D] bar; [E] write A/V + Xbuf(t+1); [F] bar;
// [G] PV MFMA.
__global__ __launch_bounds__(1024, 4)
void k_main(const float* __restrict__ X, const unsigned short* __restrict__ W2T,
            const float* __restrict__ b2, float* __restrict__ num_c,
            float* __restrict__ den_c) {
    extern __shared__ __align__(16) unsigned char smem[];
    const int tid  = threadIdx.x;
    const int lane = tid & 63;
    const int wid  = tid >> 6;
    const int l15  = lane & 15;
    const int lhi  = lane >> 4;
    const int b     = blockIdx.x >> 6;
    const int chunk = blockIdx.x & 63;
    const int copy  = blockIdx.x & (NCOPY - 1);
    const float* Xg = X + ((size_t)(b * SEQ + chunk * 512)) * DIM;

    const bool is_score = wid < 8;
    const int wv    = is_score ? wid : wid - 8;
    const int nbase = (is_score ? 0 : 256) + (wv & 3) * 64;  // Y-GEMM col base
    const int srow0 = (wv >> 2) * 32;                        // Y-GEMM s-half
    const int hp = wid >> 2;   // PV head
    const int dq = wid & 3;    // PV d-16th within head

    f32x4 pv[4];
    #pragma unroll
    for (int i = 0; i < 4; ++i) pv[i] = (f32x4){0.f, 0.f, 0.f, 0.f};
    float den_acc[4] = {0.f, 0.f, 0.f, 0.f};

    float bias[4];
    #pragma unroll
    for (int ni = 0; ni < 4; ++ni) bias[ni] = b2[nbase + ni * 16 + l15];

    float4 pf[4];
    // ---- prologue: stage tile 0 (64 rows x 256 cols fp32 -> bf16 LDS) ----
    #pragma unroll
    for (int j = 0; j < 4; ++j) {
        const int f = j * 1024 + tid;
        pf[j] = *(const float4*)(Xg + (f >> 6) * DIM + (f & 63) * 4);
    }
    #pragma unroll
    for (int j = 0; j < 4; ++j) {
        const int f = j * 1024 + tid;
        const int row = f >> 6, c4 = f & 63;
        const unsigned int lo = (unsigned int)f2bf(pf[j].x) | ((unsigned int)f2bf(pf[j].y) << 16);
        const unsigned int hi = (unsigned int)f2bf(pf[j].z) | ((unsigned int)f2bf(pf[j].w) << 16);
        const int byte = row * 512 + ((c4 * 8) ^ ((row & 7) << 4));
        *(uint2*)(smem + byte) = make_uint2(lo, hi);
    }
    __syncthreads();

    for (int t = 0; t < 8; ++t) {
        const unsigned char* xbuf = smem + (t & 1) * 32768;

        // ---- [A] prefetch next tile ----
        if (t < 7) {
            const float* Xt = Xg + (size_t)(t + 1) * 64 * DIM;
            #pragma unroll
            for (int j = 0; j < 4; ++j) {
                const int f = j * 1024 + tid;
                pf[j] = *(const float4*)(Xt + (f >> 6) * DIM + (f & 63) * 4);
            }
        }

        // ---- [B] Y-GEMM: 32 rows x 64 cols per wave, C-init = bias ----
        f32x4 acc[2][4];
        #pragma unroll
        for (int si = 0; si < 2; ++si)
            #pragma unroll
            for (int ni = 0; ni < 4; ++ni)
                acc[si][ni] = (f32x4){bias[ni], bias[ni], bias[ni], bias[ni]};

        #pragma unroll
        for (int ks = 0; ks < 8; ++ks) {
            bf16x8 afr[2];
            #pragma unroll
            for (int si = 0; si < 2; ++si) {
                const int row  = srow0 + si * 16 + l15;
                const int byte = row * 512 + ((ks * 64 + lhi * 16) ^ ((row & 7) << 4));
                afr[si] = *(const bf16x8*)(xbuf + byte);
            }
            #pragma unroll
            for (int ni = 0; ni < 4; ++ni) {
                const unsigned short* bp =
                    W2T + (size_t)(nbase + ni * 16 + l15) * 256 + ks * 32 + lhi * 8;
                const bf16x8 bfr = *(const bf16x8*)bp;
                #pragma unroll
                for (int si = 0; si < 2; ++si)
                    acc[si][ni] = __builtin_amdgcn_mfma_f32_16x16x32_bf16(
                        afr[si], bfr, acc[si][ni], 0, 0, 0);
            }
        }

        // ---- [C] softmax (score waves) / V-pack (V waves) -> pk ----
        uint2 pk[2][4];
        if (is_score) {
            #pragma unroll
            for (int si = 0; si < 2; ++si) {
                float m[4];
                #pragma unroll
                for (int r = 0; r < 4; ++r) {
                    m[r] = fmaxf(fmaxf(acc[si][0][r], acc[si][1][r]),
                                 fmaxf(acc[si][2][r], acc[si][3][r]));
                    m[r] = fmaxf(m[r], __shfl_xor(m[r], 1));
                    m[r] = fmaxf(m[r], __shfl_xor(m[r], 2));
                    m[r] = fmaxf(m[r], __shfl_xor(m[r], 4));
                    m[r] = fmaxf(m[r], __shfl_xor(m[r], 8));
                }
                float sm[4] = {0.f, 0.f, 0.f, 0.f};
                #pragma unroll
                for (int ni = 0; ni < 4; ++ni)
                    #pragma unroll
                    for (int r = 0; r < 4; ++r) {
                        acc[si][ni][r] = __expf(acc[si][ni][r] - m[r]);
                        sm[r] += acc[si][ni][r];
                    }
                #pragma unroll
                for (int r = 0; r < 4; ++r) {
                    sm[r] += __shfl_xor(sm[r], 1);
                    sm[r] += __shfl_xor(sm[r], 2);
                    sm[r] += __shfl_xor(sm[r], 4);
                    sm[r] += __shfl_xor(sm[r], 8);
                    sm[r] = 1.0f / sm[r];
                }
                #pragma unroll
                for (int ni = 0; ni < 4; ++ni) {
                    const float w0 = acc[si][ni][0] * sm[0], w1 = acc[si][ni][1] * sm[1];
                    const float w2 = acc[si][ni][2] * sm[2], w3 = acc[si][ni][3] * sm[3];
                    den_acc[ni] += (w0 + w1) + (w2 + w3);
                    pk[si][ni] = make_uint2(
                        (unsigned int)f2bf(w0) | ((unsigned int)f2bf(w1) << 16),
                        (unsigned int)f2bf(w2) | ((unsigned int)f2bf(w3) << 16));
                }
            }
        } else {
            #pragma unroll
            for (int si = 0; si < 2; ++si)
                #pragma unroll
                for (int ni = 0; ni < 4; ++ni)
                    pk[si][ni] = make_uint2(
                        (unsigned int)f2bf(acc[si][ni][0]) | ((unsigned int)f2bf(acc[si][ni][1]) << 16),
                        (unsigned int)f2bf(acc[si][ni][2]) | ((unsigned int)f2bf(acc[si][ni][3]) << 16));
        }

        // ---- [D] barrier (PV(t-1) reads done; xbuf(t+1) target free) ----
        __syncthreads();

        // ---- [E] write A/V ; write next X buf ----
        if (is_score) {
            const int h = wv & 3;
            #pragma unroll
            for (int si = 0; si < 2; ++si)
                #pragma unroll
                for (int ni = 0; ni < 4; ++ni) {
                    const int k  = ni * 16 + l15;
                    const int s0 = srow0 + si * 16 + lhi * 4;
                    const int byte = 65536 + h * 8192 + k * 128 + ((s0 * 2) ^ ((k & 7) << 4));
                    *(uint2*)(smem + byte) = pk[si][ni];
                }
        } else {
            const int dg = wv & 3;
            #pragma unroll
            for (int si = 0; si < 2; ++si)
                #pragma unroll
                for (int ni = 0; ni < 4; ++ni) {
                    const int dd = dg * 64 + ni * 16 + l15;
                    const int s0 = srow0 + si * 16 + lhi * 4;
                    const int byte = 98304 + dd * 128 + ((s0 * 2) ^ ((dd & 7) << 4));
                    *(uint2*)(smem + byte) = pk[si][ni];
                }
        }
        if (t < 7) {
            unsigned char* nbuf = smem + ((t + 1) & 1) * 32768;
            #pragma unroll
            for (int j = 0; j < 4; ++j) {
                const int f = j * 1024 + tid;
                const int row = f >> 6, c4 = f & 63;
                const unsigned int lo = (unsigned int)f2bf(pf[j].x) | ((unsigned int)f2bf(pf[j].y) << 16);
                const unsigned int hi = (unsigned int)f2bf(pf[j].z) | ((unsigned int)f2bf(pf[j].w) << 16);
                const int byte = row * 512 + ((c4 * 8) ^ ((row & 7) << 4));
                *(uint2*)(nbuf + byte) = make_uint2(lo, hi);
            }
        }

        // ---- [F] barrier (A/V + next X visible) ----
        __syncthreads();

        // ---- [G] PV: num_h[k][d] += A_h[k,s] * V[s, h*64+d]  (K=64, 2 steps) ----
        #pragma unroll
        for (int kk = 0; kk < 2; ++kk) {
            bf16x8 afr[4];
            #pragma unroll
            for (int mi = 0; mi < 4; ++mi) {
                const int k    = mi * 16 + l15;
                const int byte = 65536 + hp * 8192 + k * 128 +
                                 ((kk * 64 + lhi * 16) ^ ((k & 7) << 4));
                afr[mi] = *(const bf16x8*)(smem + byte);
            }
            const int dd   = hp * 64 + dq * 16 + l15;
            const int vb   = 98304 + dd * 128 + ((kk * 64 + lhi * 16) ^ ((dd & 7) << 4));
            const bf16x8 bfr = *(const bf16x8*)(smem + vb);
            #pragma unroll
            for (int mi = 0; mi < 4; ++mi)
                pv[mi] = __builtin_amdgcn_mfma_f32_16x16x32_bf16(afr[mi], bfr, pv[mi], 0, 0, 0);
        }
    }

    // ---- epilogue: partial accumulation into replicated copies ----
    if (is_score) {
        const int h = wv & 3;
        #pragma unroll
        for (int ni = 0; ni < 4; ++ni) {
            float v = den_acc[ni];
            v += __shfl_xor(v, 16);
            v += __shfl_xor(v, 32);
            if (lhi == 0)
                atomicAdd(&den_c[((copy * 4 + b) * NH + h) * NKS + ni * 16 + l15], v);
        }
    }
    #pragma unroll
    for (int mi = 0; mi < 4; ++mi)
        #pragma unroll
        for (int r = 0; r < 4; ++r) {
            const int k = mi * 16 + lhi * 4 + r;
            const int d = dq * 16 + l15;
            atomicAdd(&num_c[(((size_t)(copy * 4 + b) * NH + hp) * NKS + k) * DH + d],
                      pv[mi][r]);
        }
}

// ---------------- K3: sum copies; S_hat = num/(den+eps); out = LN ----------------
__global__ void k_final(const float* __restrict__ num_c, const float* __restrict__ den_c,
                        const float* __restrict__ ga, const float* __restrict__ gb,
                        float* __restrict__ out) {
    __shared__ float red1[4], red2[4];
    const int b = blockIdx.x >> 6, k = blockIdx.x & 63;
    const int t = threadIdx.x;
    const int h = t >> 6, dd = t & 63;
    float nsum = 0.f, dsum = 0.f;
    #pragma unroll
    for (int c = 0; c < NCOPY; ++c) {
        nsum += num_c[(((size_t)(c * 4 + b) * NH + h) * NKS + k) * DH + dd];
        dsum += den_c[((c * 4 + b) * NH + h) * NKS + k];
    }
    const float val = nsum / (dsum + 1e-20f);
    float s = val;
    #pragma unroll
    for (int o = 1; o <= 32; o <<= 1) s += __shfl_xor(s, o);
    if ((t & 63) == 0) red1[t >> 6] = s;
    __syncthreads();
    const float mean = (red1[0] + red1[1] + red1[2] + red1[3]) * (1.0f / DIM);
    const float d = val - mean;
    float vs = d * d;
    #pragma unroll
    for (int o = 1; o <= 32; o <<= 1) vs += __shfl_xor(vs, o);
    if ((t & 63) == 0) red2[t >> 6] = vs;
    __syncthreads();
    const float var = (red2[0] + red2[1] + red2[2] + red2[3]) * (1.0f / DIM);
    out[(size_t)(b * NKS + k) * DIM + t] = d * rsqrtf(var + 1e-5f) * ga[t] + gb[t];
}

extern "C" void kernel_launch(void* const* d_in, const int* in_sizes, int n_in,
                              void* d_out, int out_size, void* d_ws, size_t ws_size,
                              hipStream_t stream) {
    const float* X      = (const float*)d_in[0];
    const float* mu     = (const float*)d_in[1];
    const float* ln_s_g = (const float*)d_in[2];
    const float* ln_s_b = (const float*)d_in[3];
    const float* Wq     = (const float*)d_in[4];
    const float* bq     = (const float*)d_in[5];
    const float* Wk     = (const float*)d_in[6];
    const float* bk     = (const float*)d_in[7];
    const float* Wv     = (const float*)d_in[8];
    const float* bv     = (const float*)d_in[9];
    const float* ln_a_g = (const float*)d_in[10];
    const float* ln_a_b = (const float*)d_in[11];
    float* out = (float*)d_out;

    char* ws = (char*)d_ws;
    float*          Q     = (float*)(ws);                    //    65536 B
    unsigned short* W2T   = (unsigned short*)(ws + 65536);   //   262144 B
    float*          b2    = (float*)(ws + 327680);           //     2048 B
    float*          num_c = (float*)(ws + 329728);           //  4194304 B (4 copies x 1MB)
    float*          den_c = (float*)(ws + 4524032);          //    16384 B

    hipFuncSetAttribute((const void*)k_main,
                        hipFuncAttributeMaxDynamicSharedMemorySize, 131072);
    hipMemsetAsync(ws + 329728, 0, 4194304 + 16384, stream);  // zero num_c+den_c
    hipLaunchKernelGGL(k_q,     dim3(64),  dim3(256), 0, stream, mu, ln_s_g, ln_s_b, Wq, bq, Q);
    hipLaunchKernelGGL(k_fold,  dim3(512), dim3(256), 0, stream, Q, Wk, bk, Wv, bv, W2T, b2);
    hipLaunchKernelGGL(k_main,  dim3(256), dim3(1024), 131072, stream, X, W2T, b2, num_c, den_c);
    hipLaunchKernelGGL(k_final, dim3(256), dim3(256), 0, stream, num_c, den_c, ln_a_g, ln_a_b, out);
}

// Round 5
// 177.224 us; speedup vs baseline: 1.7875x; 1.7875x over previous
//
#include <hip/hip_runtime.h>
#include <hip/hip_bf16.h>

#define DIM   256
#define DH    64
#define NKS   64      // K_SLOTS
#define NH    4       // HEADS
#define SEQ   32768
#define NCOPY 4       // replicated global accumulators

typedef float f32x4  __attribute__((ext_vector_type(4)));
typedef short bf16x8 __attribute__((ext_vector_type(8)));

__device__ __forceinline__ unsigned short f2bf(float f) {
    union { float f; unsigned int u; } v; v.f = f;
    return (unsigned short)((v.u + 0x7FFFu + ((v.u >> 16) & 1u)) >> 16);  // RNE
}
__device__ __forceinline__ unsigned int f2bf2(float lo, float hi) {
    return (unsigned int)f2bf(lo) | ((unsigned int)f2bf(hi) << 16);
}

// ---------------- K0: Q = LN(mu) @ Wq + bq  -> Q[64][256] fp32 ----------------
__global__ void k_q(const float* __restrict__ mu, const float* __restrict__ g,
                    const float* __restrict__ bb, const float* __restrict__ Wq,
                    const float* __restrict__ bq, float* __restrict__ Q) {
    __shared__ float nrm[DIM];
    __shared__ float red1[4], red2[4];
    const int k = blockIdx.x, t = threadIdx.x;
    float x = mu[k * DIM + t];
    float s = x;
    #pragma unroll
    for (int o = 1; o <= 32; o <<= 1) s += __shfl_xor(s, o);
    if ((t & 63) == 0) red1[t >> 6] = s;
    __syncthreads();
    const float mean = (red1[0] + red1[1] + red1[2] + red1[3]) * (1.0f / DIM);
    const float d = x - mean;
    float vs = d * d;
    #pragma unroll
    for (int o = 1; o <= 32; o <<= 1) vs += __shfl_xor(vs, o);
    if ((t & 63) == 0) red2[t >> 6] = vs;
    __syncthreads();
    const float var = (red2[0] + red2[1] + red2[2] + red2[3]) * (1.0f / DIM);
    nrm[t] = d * rsqrtf(var + 1e-5f) * g[t] + bb[t];
    __syncthreads();
    float acc = bq[t];
    for (int c = 0; c < DIM; ++c) acc += nrm[c] * Wq[c * DIM + t];
    Q[k * DIM + t] = acc;
}

// ---- K1: fold scores matrix + transpose. W2T[n][c] (bf16, c contiguous) ----
__global__ void k_fold(const float* __restrict__ Q, const float* __restrict__ Wk,
                       const float* __restrict__ bk, const float* __restrict__ Wv,
                       const float* __restrict__ bv,
                       unsigned short* __restrict__ W2T, float* __restrict__ b2) {
    const int n = blockIdx.x, t = threadIdx.x;
    __shared__ float q[DH];
    if (n < 256) {
        const int h = n >> 6, k = n & 63;
        if (t < DH) q[t] = Q[k * DIM + h * DH + t];
        __syncthreads();
        float acc = 0.f;
        #pragma unroll 8
        for (int d0 = 0; d0 < DH; ++d0) acc += Wk[t * DIM + h * DH + d0] * q[d0];
        W2T[n * 256 + t] = f2bf(acc * 0.125f);
        if (t == 0) {
            float ba = 0.f;
            for (int d0 = 0; d0 < DH; ++d0) ba += bk[h * DH + d0] * q[d0];
            b2[n] = ba * 0.125f;
        }
    } else {
        const int col = n - 256;
        W2T[n * 256 + t] = f2bf(Wv[t * DIM + col]);
        if (t == 0) b2[n] = bv[col];
    }
}

// ---------------- K2: fused main kernel, 16 waves, B-panel in registers ----------------
// Grid 512 = 4b x 128chunks (256 rows = 8 tiles of 32). 1024 thr = 16 waves.
// Each wave owns 32 Y-cols (wid*32): waves 0-7 scores (h=wid>>1, slot-half=wid&1),
// waves 8-15 V-cols. B-panel (32 cols x 256 k bf16) = 64 VGPR, loaded ONCE.
// Softmax: NO max-subtract (scores ~ +-1 by construction: |W2T|~0.3-scale rows,
// bf16 X ~ N(0,1), scale 0.125 -> sigma~0.1; exp overflow-safe). Slot-sum crosses
// the wave pair via Ssc LDS; 1/S folded into V rows (A_lds holds raw exp).
// LDS (75776 B dynamic): Xbuf0 @0, Xbuf1 @16384 (32 rows x 512 B bf16, XOR swz),
//   A @32768 ([4h][64k] rows, stride 80 B, 32 s bf16), V @53248 ([256d] stride 80),
//   Ssc @73728 (dbuf[2][4h][2sh][32row] f32).
// Per tile: [A] prefetch X(t+1)->pf(8 reg); [B] Y-GEMM (B from regs, C-init=bias);
// [C] exp + partial slot-sums -> Ssc; [D] bar; [E] read S, den+=, write A (raw exp),
//     write V*1/S, write Xbuf(t+1); [F] bar; [G] PV MFMA (K=32).
// Reg budget (128 hard cap at 1024 thr): bfr 64 + acc 16 + pv 16 + pf 8 + misc ~20.
__global__ __launch_bounds__(1024)
void k_main(const float* __restrict__ X, const unsigned short* __restrict__ W2T,
            const float* __restrict__ b2, float* __restrict__ num_c,
            float* __restrict__ den_c) {
    extern __shared__ __align__(16) unsigned char smem[];
    const int AB = 32768, VB = 53248, SB = 73728;
    const int tid  = threadIdx.x;
    const int lane = tid & 63;
    const int wid  = tid >> 6;
    const int l15  = lane & 15;
    const int lhi  = lane >> 4;
    const int b     = blockIdx.x >> 7;
    const int chunk = blockIdx.x & 127;
    const int copy  = blockIdx.x & (NCOPY - 1);
    const float* Xg = X + ((size_t)(b * SEQ + chunk * 256)) * DIM;

    const bool is_score = wid < 8;
    const int h_sc  = wid >> 1;          // score head
    const int sh    = wid & 1;           // slot half
    const int vg    = wid - 8;           // V col-group
    const int h_v   = vg >> 1;           // V wave's head
    const int nbase = wid * 32;          // Y col base in W2T (works for both roles)
    const int hp = wid >> 2;             // PV head
    const int dq = wid & 3;              // PV d-quarter

    // ---- B-panel: 16 frags x 16 B = 64 VGPR, loaded once ----
    bf16x8 bfr[8][2];
    #pragma unroll
    for (int ks = 0; ks < 8; ++ks)
        #pragma unroll
        for (int ni = 0; ni < 2; ++ni)
            bfr[ks][ni] = *(const bf16x8*)(W2T + (size_t)(nbase + ni * 16 + l15) * 256
                                           + ks * 32 + lhi * 8);
    float bias[2];
    #pragma unroll
    for (int ni = 0; ni < 2; ++ni) bias[ni] = b2[nbase + ni * 16 + l15];

    f32x4 pv[4];
    #pragma unroll
    for (int i = 0; i < 4; ++i) pv[i] = (f32x4){0.f, 0.f, 0.f, 0.f};
    float den_acc[2] = {0.f, 0.f};

    float4 pf[2];
    // ---- prologue: stage tile 0 (32 rows x 256 fp32 -> bf16, swz) ----
    #pragma unroll
    for (int j = 0; j < 2; ++j) {
        const int f = j * 1024 + tid;
        pf[j] = *(const float4*)(Xg + (f >> 6) * DIM + (f & 63) * 4);
    }
    #pragma unroll
    for (int j = 0; j < 2; ++j) {
        const int f = j * 1024 + tid;
        const int row = f >> 6, c4 = f & 63;
        const int byte = row * 512 + ((c4 * 8) ^ ((row & 7) << 4));
        *(uint2*)(smem + byte) = make_uint2(f2bf2(pf[j].x, pf[j].y), f2bf2(pf[j].z, pf[j].w));
    }
    __syncthreads();

    for (int t = 0; t < 8; ++t) {
        const int tb = t & 1;
        const unsigned char* xbuf = smem + tb * 16384;

        // ---- [A] prefetch next tile ----
        if (t < 7) {
            const float* Xt = Xg + (size_t)(t + 1) * 32 * DIM;
            #pragma unroll
            for (int j = 0; j < 2; ++j) {
                const int f = j * 1024 + tid;
                pf[j] = *(const float4*)(Xt + (f >> 6) * DIM + (f & 63) * 4);
            }
        }

        // ---- [B] Y-GEMM: 32 rows x 32 cols, B from registers ----
        f32x4 acc[2][2];
        #pragma unroll
        for (int si = 0; si < 2; ++si)
            #pragma unroll
            for (int ni = 0; ni < 2; ++ni)
                acc[si][ni] = (f32x4){bias[ni], bias[ni], bias[ni], bias[ni]};
        #pragma unroll
        for (int ks = 0; ks < 8; ++ks) {
            #pragma unroll
            for (int si = 0; si < 2; ++si) {
                const int row  = si * 16 + l15;
                const int byte = row * 512 + ((ks * 64 + lhi * 16) ^ ((row & 7) << 4));
                const bf16x8 afr = *(const bf16x8*)(xbuf + byte);
                #pragma unroll
                for (int ni = 0; ni < 2; ++ni)
                    acc[si][ni] = __builtin_amdgcn_mfma_f32_16x16x32_bf16(
                        afr, bfr[ks][ni], acc[si][ni], 0, 0, 0);
            }
        }

        // ---- [C] exp (no max) + partial slot-sums -> Ssc ----
        if (is_score) {
            #pragma unroll
            for (int si = 0; si < 2; ++si) {
                #pragma unroll
                for (int ni = 0; ni < 2; ++ni)
                    #pragma unroll
                    for (int r = 0; r < 4; ++r)
                        acc[si][ni][r] = __expf(acc[si][ni][r]);
                #pragma unroll
                for (int r = 0; r < 4; ++r) {
                    float p = acc[si][0][r] + acc[si][1][r];
                    p += __shfl_xor(p, 1);
                    p += __shfl_xor(p, 2);
                    p += __shfl_xor(p, 4);
                    p += __shfl_xor(p, 8);
                    if (l15 == 0)
                        *(float*)(smem + SB + (((tb * 4 + h_sc) * 2 + sh) * 32
                                               + si * 16 + lhi * 4 + r) * 4) = p;
                }
            }
        }

        // ---- [D] barrier ----
        __syncthreads();

        // ---- [E] read S; write A (raw exp) / V (scaled); write next X ----
        {
            const int hh = is_score ? h_sc : h_v;
            #pragma unroll
            for (int si = 0; si < 2; ++si) {
                const int sbase = SB + ((tb * 4 + hh) * 2) * 128 + (si * 16 + lhi * 4) * 4;
                const f32x4 s0 = *(const f32x4*)(smem + sbase);
                const f32x4 s1 = *(const f32x4*)(smem + sbase + 128);
                float sinv[4];
                #pragma unroll
                for (int r = 0; r < 4; ++r) sinv[r] = 1.0f / (s0[r] + s1[r]);
                if (is_score) {
                    #pragma unroll
                    for (int ni = 0; ni < 2; ++ni) {
                        den_acc[ni] += acc[si][ni][0] * sinv[0] + acc[si][ni][1] * sinv[1]
                                     + acc[si][ni][2] * sinv[2] + acc[si][ni][3] * sinv[3];
                        const int k = sh * 32 + ni * 16 + l15;
                        const int byte = AB + (h_sc * 64 + k) * 80 + (si * 16 + lhi * 4) * 2;
                        *(uint2*)(smem + byte) = make_uint2(
                            f2bf2(acc[si][ni][0], acc[si][ni][1]),
                            f2bf2(acc[si][ni][2], acc[si][ni][3]));
                    }
                } else {
                    #pragma unroll
                    for (int ni = 0; ni < 2; ++ni) {
                        const int d = vg * 32 + ni * 16 + l15;
                        const int byte = VB + d * 80 + (si * 16 + lhi * 4) * 2;
                        *(uint2*)(smem + byte) = make_uint2(
                            f2bf2(acc[si][ni][0] * sinv[0], acc[si][ni][1] * sinv[1]),
                            f2bf2(acc[si][ni][2] * sinv[2], acc[si][ni][3] * sinv[3]));
                    }
                }
            }
        }
        if (t < 7) {
            unsigned char* nbuf = smem + (tb ^ 1) * 16384;
            #pragma unroll
            for (int j = 0; j < 2; ++j) {
                const int f = j * 1024 + tid;
                const int row = f >> 6, c4 = f & 63;
                const int byte = row * 512 + ((c4 * 8) ^ ((row & 7) << 4));
                *(uint2*)(nbuf + byte) = make_uint2(f2bf2(pf[j].x, pf[j].y),
                                                    f2bf2(pf[j].z, pf[j].w));
            }
        }

        // ---- [F] barrier ----
        __syncthreads();

        // ---- [G] PV: pv[h][k][dq*16..] += A_h[k,s] * Vs[s,d]  (K=32) ----
        {
            const unsigned char* Ah = smem + AB + hp * 5120;  // 64 rows * 80 B
            bf16x8 afr[4];
            #pragma unroll
            for (int mi = 0; mi < 4; ++mi)
                afr[mi] = *(const bf16x8*)(Ah + (mi * 16 + l15) * 80 + lhi * 16);
            const bf16x8 vfr = *(const bf16x8*)(smem + VB
                                + (hp * 64 + dq * 16 + l15) * 80 + lhi * 16);
            #pragma unroll
            for (int mi = 0; mi < 4; ++mi)
                pv[mi] = __builtin_amdgcn_mfma_f32_16x16x32_bf16(afr[mi], vfr, pv[mi], 0, 0, 0);
        }
    }

    // ---- epilogue ----
    if (is_score) {
        #pragma unroll
        for (int ni = 0; ni < 2; ++ni) {
            float v = den_acc[ni];
            v += __shfl_xor(v, 16);
            v += __shfl_xor(v, 32);
            if (lhi == 0)
                atomicAdd(&den_c[((copy * 4 + b) * NH + h_sc) * NKS
                                 + sh * 32 + ni * 16 + l15], v);
        }
    }
    #pragma unroll
    for (int mi = 0; mi < 4; ++mi)
        #pragma unroll
        for (int r = 0; r < 4; ++r) {
            const int k = mi * 16 + lhi * 4 + r;
            const int d = dq * 16 + l15;
            atomicAdd(&num_c[(((size_t)(copy * 4 + b) * NH + hp) * NKS + k) * DH + d],
                      pv[mi][r]);
        }
}

// ---------------- K3: sum copies; S_hat = num/(den+eps); out = LN ----------------
__global__ void k_final(const float* __restrict__ num_c, const float* __restrict__ den_c,
                        const float* __restrict__ ga, const float* __restrict__ gb,
                        float* __restrict__ out) {
    __shared__ float red1[4], red2[4];
    const int b = blockIdx.x >> 6, k = blockIdx.x & 63;
    const int t = threadIdx.x;
    const int h = t >> 6, dd = t & 63;
    float nsum = 0.f, dsum = 0.f;
    #pragma unroll
    for (int c = 0; c < NCOPY; ++c) {
        nsum += num_c[(((size_t)(c * 4 + b) * NH + h) * NKS + k) * DH + dd];
        dsum += den_c[((c * 4 + b) * NH + h) * NKS + k];
    }
    const float val = nsum / (dsum + 1e-20f);
    float s = val;
    #pragma unroll
    for (int o = 1; o <= 32; o <<= 1) s += __shfl_xor(s, o);
    if ((t & 63) == 0) red1[t >> 6] = s;
    __syncthreads();
    const float mean = (red1[0] + red1[1] + red1[2] + red1[3]) * (1.0f / DIM);
    const float d = val - mean;
    float vs = d * d;
    #pragma unroll
    for (int o = 1; o <= 32; o <<= 1) vs += __shfl_xor(vs, o);
    if ((t & 63) == 0) red2[t >> 6] = vs;
    __syncthreads();
    const float var = (red2[0] + red2[1] + red2[2] + red2[3]) * (1.0f / DIM);
    out[(size_t)(b * NKS + k) * DIM + t] = d * rsqrtf(var + 1e-5f) * ga[t] + gb[t];
}

extern "C" void kernel_launch(void* const* d_in, const int* in_sizes, int n_in,
                              void* d_out, int out_size, void* d_ws, size_t ws_size,
                              hipStream_t stream) {
    const float* X      = (const float*)d_in[0];
    const float* mu     = (const float*)d_in[1];
    const float* ln_s_g = (const float*)d_in[2];
    const float* ln_s_b = (const float*)d_in[3];
    const float* Wq     = (const float*)d_in[4];
    const float* bq     = (const float*)d_in[5];
    const float* Wk     = (const float*)d_in[6];
    const float* bk     = (const float*)d_in[7];
    const float* Wv     = (const float*)d_in[8];
    const float* bv     = (const float*)d_in[9];
    const float* ln_a_g = (const float*)d_in[10];
    const float* ln_a_b = (const float*)d_in[11];
    float* out = (float*)d_out;

    char* ws = (char*)d_ws;
    float*          Q     = (float*)(ws);                    //    65536 B
    unsigned short* W2T   = (unsigned short*)(ws + 65536);   //   262144 B
    float*          b2    = (float*)(ws + 327680);           //     2048 B
    float*          num_c = (float*)(ws + 329728);           //  4194304 B
    float*          den_c = (float*)(ws + 4524032);          //    16384 B

    hipFuncSetAttribute((const void*)k_main,
                        hipFuncAttributeMaxDynamicSharedMemorySize, 75776);
    hipMemsetAsync(ws + 329728, 0, 4194304 + 16384, stream);  // zero num_c+den_c
    hipLaunchKernelGGL(k_q,     dim3(64),  dim3(256), 0, stream, mu, ln_s_g, ln_s_b, Wq, bq, Q);
    hipLaunchKernelGGL(k_fold,  dim3(512), dim3(256), 0, stream, Q, Wk, bk, Wv, bv, W2T, b2);
    hipLaunchKernelGGL(k_main,  dim3(512), dim3(1024), 75776, stream, X, W2T, b2, num_c, den_c);
    hipLaunchKernelGGL(k_final, dim3(256), dim3(256), 0, stream, num_c, den_c, ln_a_g, ln_a_b, out);
}

// Round 7
// 174.449 us; speedup vs baseline: 1.8159x; 1.0159x over previous
//
#include <hip/hip_runtime.h>
#include <hip/hip_bf16.h>

#define DIM   256
#define DH    64
#define NKS   64      // K_SLOTS
#define NH    4       // HEADS
#define SEQ   32768
#define NCOPY 8       // one accumulator copy per XCD (blockIdx%8 == XCD)

typedef float f32x4  __attribute__((ext_vector_type(4)));
typedef short bf16x8 __attribute__((ext_vector_type(8)));

__device__ __forceinline__ unsigned short f2bf(float f) {
    union { __hip_bfloat16 b; unsigned short u; } v;
    v.b = __float2bfloat16(f);   // RNE; compiler emits native cvt
    return v.u;
}
__device__ __forceinline__ unsigned int f2bf2(float lo, float hi) {
    return (unsigned int)f2bf(lo) | ((unsigned int)f2bf(hi) << 16);
}

// ---------------- K0: Q = LN(mu) @ Wq + bq  -> Q[64][256] fp32 ----------------
__global__ void k_q(const float* __restrict__ mu, const float* __restrict__ g,
                    const float* __restrict__ bb, const float* __restrict__ Wq,
                    const float* __restrict__ bq, float* __restrict__ Q) {
    __shared__ float nrm[DIM];
    __shared__ float red1[4], red2[4];
    const int k = blockIdx.x, t = threadIdx.x;
    float x = mu[k * DIM + t];
    float s = x;
    #pragma unroll
    for (int o = 1; o <= 32; o <<= 1) s += __shfl_xor(s, o);
    if ((t & 63) == 0) red1[t >> 6] = s;
    __syncthreads();
    const float mean = (red1[0] + red1[1] + red1[2] + red1[3]) * (1.0f / DIM);
    const float d = x - mean;
    float vs = d * d;
    #pragma unroll
    for (int o = 1; o <= 32; o <<= 1) vs += __shfl_xor(vs, o);
    if ((t & 63) == 0) red2[t >> 6] = vs;
    __syncthreads();
    const float var = (red2[0] + red2[1] + red2[2] + red2[3]) * (1.0f / DIM);
    nrm[t] = d * rsqrtf(var + 1e-5f) * g[t] + bb[t];
    __syncthreads();
    float acc = bq[t];
    for (int c = 0; c < DIM; ++c) acc += nrm[c] * Wq[c * DIM + t];
    Q[k * DIM + t] = acc;
}

// ---- K1: fold scores matrix + transpose. W2T[n][c] (bf16, c contiguous) ----
__global__ void k_fold(const float* __restrict__ Q, const float* __restrict__ Wk,
                       const float* __restrict__ bk, const float* __restrict__ Wv,
                       const float* __restrict__ bv,
                       unsigned short* __restrict__ W2T, float* __restrict__ b2) {
    const int n = blockIdx.x, t = threadIdx.x;
    __shared__ float q[DH];
    if (n < 256) {
        const int h = n >> 6, k = n & 63;
        if (t < DH) q[t] = Q[k * DIM + h * DH + t];
        __syncthreads();
        float acc = 0.f;
        #pragma unroll 8
        for (int d0 = 0; d0 < DH; ++d0) acc += Wk[t * DIM + h * DH + d0] * q[d0];
        W2T[n * 256 + t] = f2bf(acc * 0.125f);
        if (t == 0) {
            float ba = 0.f;
            for (int d0 = 0; d0 < DH; ++d0) ba += bk[h * DH + d0] * q[d0];
            b2[n] = ba * 0.125f;
        }
    } else {
        const int col = n - 256;
        W2T[n * 256 + t] = f2bf(Wv[t * DIM + col]);
        if (t == 0) b2[n] = bv[col];
    }
}

// ---------------- K2: fused main kernel ----------------
// Grid 512 = 4b x 128chunks (256 rows = 8 tiles of 32). 1024 thr = 16 waves.
// Wave w owns 32 Y-cols: w<8 scores (h=w>>1, slot-half=w&1), w>=8 V-cols.
// B-panel in regs (64 VGPR). No max-subtract softmax (scores ~N(0,~0.1)).
// LDS (67584 B): Xbuf0 @0, Xbuf1 @16384 (32rows x 512B, XOR swz),
//   A @32768 ([4h][64k] rows x 64B), V @49152 ([256d] rows x 64B),
//   Ssc @65536 (dbuf [2][4h][2sh][32row] f32 = 2048 B -- MUST be 2048:
//   round-6 NaN was this region under-allocated by 1024).
// A/V row swizzle: byte_off ^ ((row>>1)&3)<<4 -- spreads PV's 16-lane
// ds_read_b128 over all 8 16B-slots (slot = 4*(row&1) + ((row>>1)&3)),
// 2-way max (free, m136). (row&3)<<4 only reached 4 slots -> 4-way.
__global__ __launch_bounds__(1024)
void k_main(const float* __restrict__ X, const unsigned short* __restrict__ W2T,
            const float* __restrict__ b2, float* __restrict__ num_c,
            float* __restrict__ den_c) {
    extern __shared__ __align__(16) unsigned char smem[];
    const int AB = 32768, VB = 49152, SB = 65536;
    const int tid  = threadIdx.x;
    const int lane = tid & 63;
    const int wid  = tid >> 6;
    const int l15  = lane & 15;
    const int lhi  = lane >> 4;
    const int b     = blockIdx.x >> 7;
    const int chunk = blockIdx.x & 127;
    const int copy  = blockIdx.x & (NCOPY - 1);
    const float* Xg = X + ((size_t)(b * SEQ + chunk * 256)) * DIM;

    const bool is_score = wid < 8;
    const int h_sc  = wid >> 1;          // score head
    const int sh    = wid & 1;           // slot half
    const int vg    = wid - 8;           // V col-group
    const int h_v   = vg >> 1;           // V wave's head
    const int nbase = wid * 32;          // Y col base in W2T
    const int hp = wid >> 2;             // PV head
    const int dq = wid & 3;              // PV d-quarter

    // ---- B-panel: 16 frags x 16 B = 64 regs, loaded once ----
    bf16x8 bfr[8][2];
    #pragma unroll
    for (int ks = 0; ks < 8; ++ks)
        #pragma unroll
        for (int ni = 0; ni < 2; ++ni)
            bfr[ks][ni] = *(const bf16x8*)(W2T + (size_t)(nbase + ni * 16 + l15) * 256
                                           + ks * 32 + lhi * 8);
    float bias[2];
    #pragma unroll
    for (int ni = 0; ni < 2; ++ni) bias[ni] = b2[nbase + ni * 16 + l15];

    f32x4 pv[4];
    #pragma unroll
    for (int i = 0; i < 4; ++i) pv[i] = (f32x4){0.f, 0.f, 0.f, 0.f};
    float den_acc[2] = {0.f, 0.f};

    float4 pf[2];
    // ---- prologue: stage tile 0 ----
    #pragma unroll
    for (int j = 0; j < 2; ++j) {
        const int f = j * 1024 + tid;
        pf[j] = *(const float4*)(Xg + (f >> 6) * DIM + (f & 63) * 4);
    }
    #pragma unroll
    for (int j = 0; j < 2; ++j) {
        const int f = j * 1024 + tid;
        const int row = f >> 6, c4 = f & 63;
        const int byte = row * 512 + ((c4 * 8) ^ ((row & 7) << 4));
        *(uint2*)(smem + byte) = make_uint2(f2bf2(pf[j].x, pf[j].y), f2bf2(pf[j].z, pf[j].w));
    }
    __syncthreads();

    for (int t = 0; t < 8; ++t) {
        const int tb = t & 1;
        const unsigned char* xbuf = smem + tb * 16384;

        // ---- [A] prefetch next tile ----
        if (t < 7) {
            const float* Xt = Xg + (size_t)(t + 1) * 32 * DIM;
            #pragma unroll
            for (int j = 0; j < 2; ++j) {
                const int f = j * 1024 + tid;
                pf[j] = *(const float4*)(Xt + (f >> 6) * DIM + (f & 63) * 4);
            }
        }

        // ---- [B] Y-GEMM: 32 rows x 32 cols, B from registers ----
        f32x4 acc[2][2];
        #pragma unroll
        for (int si = 0; si < 2; ++si)
            #pragma unroll
            for (int ni = 0; ni < 2; ++ni)
                acc[si][ni] = (f32x4){bias[ni], bias[ni], bias[ni], bias[ni]};
        #pragma unroll
        for (int ks = 0; ks < 8; ++ks) {
            #pragma unroll
            for (int si = 0; si < 2; ++si) {
                const int row  = si * 16 + l15;
                const int byte = row * 512 + ((ks * 64 + lhi * 16) ^ ((row & 7) << 4));
                const bf16x8 afr = *(const bf16x8*)(xbuf + byte);
                #pragma unroll
                for (int ni = 0; ni < 2; ++ni)
                    acc[si][ni] = __builtin_amdgcn_mfma_f32_16x16x32_bf16(
                        afr, bfr[ks][ni], acc[si][ni], 0, 0, 0);
            }
        }

        // ---- [C] exp (no max) + partial slot-sums -> Ssc ----
        if (is_score) {
            #pragma unroll
            for (int si = 0; si < 2; ++si) {
                #pragma unroll
                for (int ni = 0; ni < 2; ++ni)
                    #pragma unroll
                    for (int r = 0; r < 4; ++r)
                        acc[si][ni][r] = __expf(acc[si][ni][r]);
                #pragma unroll
                for (int r = 0; r < 4; ++r) {
                    float p = acc[si][0][r] + acc[si][1][r];
                    p += __shfl_xor(p, 1);
                    p += __shfl_xor(p, 2);
                    p += __shfl_xor(p, 4);
                    p += __shfl_xor(p, 8);
                    if (l15 == 0)
                        *(float*)(smem + SB + (((tb * 4 + h_sc) * 2 + sh) * 32
                                               + si * 16 + lhi * 4 + r) * 4) = p;
                }
            }
        }

        // ---- [D] barrier ----
        __syncthreads();

        // ---- [E] read S; write A (raw exp) / V (scaled); write next X ----
        {
            const int hh = is_score ? h_sc : h_v;
            #pragma unroll
            for (int si = 0; si < 2; ++si) {
                const int sbase = SB + ((tb * 4 + hh) * 2) * 128 + (si * 16 + lhi * 4) * 4;
                const f32x4 s0 = *(const f32x4*)(smem + sbase);
                const f32x4 s1 = *(const f32x4*)(smem + sbase + 128);
                float sinv[4];
                #pragma unroll
                for (int r = 0; r < 4; ++r) sinv[r] = 1.0f / (s0[r] + s1[r]);
                if (is_score) {
                    #pragma unroll
                    for (int ni = 0; ni < 2; ++ni) {
                        den_acc[ni] += acc[si][ni][0] * sinv[0] + acc[si][ni][1] * sinv[1]
                                     + acc[si][ni][2] * sinv[2] + acc[si][ni][3] * sinv[3];
                        const int k = sh * 32 + ni * 16 + l15;
                        const int byte = AB + (h_sc * 64 + k) * 64
                                       + ((si * 32 + lhi * 8) ^ (((k >> 1) & 3) << 4));
                        *(uint2*)(smem + byte) = make_uint2(
                            f2bf2(acc[si][ni][0], acc[si][ni][1]),
                            f2bf2(acc[si][ni][2], acc[si][ni][3]));
                    }
                } else {
                    #pragma unroll
                    for (int ni = 0; ni < 2; ++ni) {
                        const int d = vg * 32 + ni * 16 + l15;
                        const int byte = VB + d * 64
                                       + ((si * 32 + lhi * 8) ^ (((d >> 1) & 3) << 4));
                        *(uint2*)(smem + byte) = make_uint2(
                            f2bf2(acc[si][ni][0] * sinv[0], acc[si][ni][1] * sinv[1]),
                            f2bf2(acc[si][ni][2] * sinv[2], acc[si][ni][3] * sinv[3]));
                    }
                }
            }
        }
        if (t < 7) {
            unsigned char* nbuf = smem + (tb ^ 1) * 16384;
            #pragma unroll
            for (int j = 0; j < 2; ++j) {
                const int f = j * 1024 + tid;
                const int row = f >> 6, c4 = f & 63;
                const int byte = row * 512 + ((c4 * 8) ^ ((row & 7) << 4));
                *(uint2*)(nbuf + byte) = make_uint2(f2bf2(pf[j].x, pf[j].y),
                                                    f2bf2(pf[j].z, pf[j].w));
            }
        }

        // ---- [F] barrier ----
        __syncthreads();

        // ---- [G] PV: pv[k-rows][dq*16..] += A_hp[k,s] * Vs[s,d]  (K=32) ----
        {
            bf16x8 afr[4];
            #pragma unroll
            for (int mi = 0; mi < 4; ++mi) {
                const int k = mi * 16 + l15;
                afr[mi] = *(const bf16x8*)(smem + AB + (hp * 64 + k) * 64
                                           + ((lhi * 16) ^ (((k >> 1) & 3) << 4)));
            }
            const int d = hp * 64 + dq * 16 + l15;
            const bf16x8 vfr = *(const bf16x8*)(smem + VB + d * 64
                                                + ((lhi * 16) ^ (((d >> 1) & 3) << 4)));
            #pragma unroll
            for (int mi = 0; mi < 4; ++mi)
                pv[mi] = __builtin_amdgcn_mfma_f32_16x16x32_bf16(afr[mi], vfr, pv[mi], 0, 0, 0);
        }
    }

    // ---- epilogue: XCD-affine replicated atomics ----
    if (is_score) {
        #pragma unroll
        for (int ni = 0; ni < 2; ++ni) {
            float v = den_acc[ni];
            v += __shfl_xor(v, 16);
            v += __shfl_xor(v, 32);
            if (lhi == 0)
                atomicAdd(&den_c[((copy * 4 + b) * NH + h_sc) * NKS
                                 + sh * 32 + ni * 16 + l15], v);
        }
    }
    #pragma unroll
    for (int mi = 0; mi < 4; ++mi)
        #pragma unroll
        for (int r = 0; r < 4; ++r) {
            const int k = mi * 16 + lhi * 4 + r;
            const int d = dq * 16 + l15;
            atomicAdd(&num_c[(((size_t)(copy * 4 + b) * NH + hp) * NKS + k) * DH + d],
                      pv[mi][r]);
        }
}

// ---------------- K3: sum copies; S_hat = num/(den+eps); out = LN ----------------
__global__ void k_final(const float* __restrict__ num_c, const float* __restrict__ den_c,
                        const float* __restrict__ ga, const float* __restrict__ gb,
                        float* __restrict__ out) {
    __shared__ float red1[4], red2[4];
    const int b = blockIdx.x >> 6, k = blockIdx.x & 63;
    const int t = threadIdx.x;
    const int h = t >> 6, dd = t & 63;
    float nsum = 0.f, dsum = 0.f;
    #pragma unroll
    for (int c = 0; c < NCOPY; ++c) {
        nsum += num_c[(((size_t)(c * 4 + b) * NH + h) * NKS + k) * DH + dd];
        dsum += den_c[((c * 4 + b) * NH + h) * NKS + k];
    }
    const float val = nsum / (dsum + 1e-20f);
    float s = val;
    #pragma unroll
    for (int o = 1; o <= 32; o <<= 1) s += __shfl_xor(s, o);
    if ((t & 63) == 0) red1[t >> 6] = s;
    __syncthreads();
    const float mean = (red1[0] + red1[1] + red1[2] + red1[3]) * (1.0f / DIM);
    const float d = val - mean;
    float vs = d * d;
    #pragma unroll
    for (int o = 1; o <= 32; o <<= 1) vs += __shfl_xor(vs, o);
    if ((t & 63) == 0) red2[t >> 6] = vs;
    __syncthreads();
    const float var = (red2[0] + red2[1] + red2[2] + red2[3]) * (1.0f / DIM);
    out[(size_t)(b * NKS + k) * DIM + t] = d * rsqrtf(var + 1e-5f) * ga[t] + gb[t];
}

extern "C" void kernel_launch(void* const* d_in, const int* in_sizes, int n_in,
                              void* d_out, int out_size, void* d_ws, size_t ws_size,
                              hipStream_t stream) {
    const float* X      = (const float*)d_in[0];
    const float* mu     = (const float*)d_in[1];
    const float* ln_s_g = (const float*)d_in[2];
    const float* ln_s_b = (const float*)d_in[3];
    const float* Wq     = (const float*)d_in[4];
    const float* bq     = (const float*)d_in[5];
    const float* Wk     = (const float*)d_in[6];
    const float* bk     = (const float*)d_in[7];
    const float* Wv     = (const float*)d_in[8];
    const float* bv     = (const float*)d_in[9];
    const float* ln_a_g = (const float*)d_in[10];
    const float* ln_a_b = (const float*)d_in[11];
    float* out = (float*)d_out;

    char* ws = (char*)d_ws;
    float*          Q     = (float*)(ws);                    //    65536 B
    unsigned short* W2T   = (unsigned short*)(ws + 65536);   //   262144 B
    float*          b2    = (float*)(ws + 327680);           //     2048 B
    float*          num_c = (float*)(ws + 329728);           //  2097152 B (32 slots x 64KB)
    float*          den_c = (float*)(ws + 2426880);          //    32768 B

    hipFuncSetAttribute((const void*)k_main,
                        hipFuncAttributeMaxDynamicSharedMemorySize, 67584);
    hipMemsetAsync(ws + 329728, 0, 2097152 + 32768, stream);  // zero num_c+den_c
    hipLaunchKernelGGL(k_q,     dim3(64),  dim3(256), 0, stream, mu, ln_s_g, ln_s_b, Wq, bq, Q);
    hipLaunchKernelGGL(k_fold,  dim3(512), dim3(256), 0, stream, Q, Wk, bk, Wv, bv, W2T, b2);
    hipLaunchKernelGGL(k_main,  dim3(512), dim3(1024), 67584, stream, X, W2T, b2, num_c, den_c);
    hipLaunchKernelGGL(k_final, dim3(256), dim3(256), 0, stream, num_c, den_c, ln_a_g, ln_a_b, out);
}

// Round 8
// 150.308 us; speedup vs baseline: 2.1075x; 1.1606x over previous
//
#include <hip/hip_runtime.h>
#include <hip/hip_bf16.h>

#define DIM   256
#define DH    64
#define NKS   64      // K_SLOTS
#define NH    4       // HEADS
#define SEQ   32768
#define NCOPY 8       // fallback path: one accumulator copy per XCD

typedef float f32x4  __attribute__((ext_vector_type(4)));
typedef short bf16x8 __attribute__((ext_vector_type(8)));

__device__ __forceinline__ unsigned short f2bf(float f) {
    union { __hip_bfloat16 b; unsigned short u; } v;
    v.b = __float2bfloat16(f);
    return v.u;
}
__device__ __forceinline__ unsigned int f2bf2(float lo, float hi) {
    return (unsigned int)f2bf(lo) | ((unsigned int)f2bf(hi) << 16);
}

// ---------------- K0: Q = LN(mu) @ Wq + bq  -> Q[64][256] fp32 ----------------
__global__ void k_q(const float* __restrict__ mu, const float* __restrict__ g,
                    const float* __restrict__ bb, const float* __restrict__ Wq,
                    const float* __restrict__ bq, float* __restrict__ Q) {
    __shared__ float nrm[DIM];
    __shared__ float red1[4], red2[4];
    const int k = blockIdx.x, t = threadIdx.x;
    float x = mu[k * DIM + t];
    float s = x;
    #pragma unroll
    for (int o = 1; o <= 32; o <<= 1) s += __shfl_xor(s, o);
    if ((t & 63) == 0) red1[t >> 6] = s;
    __syncthreads();
    const float mean = (red1[0] + red1[1] + red1[2] + red1[3]) * (1.0f / DIM);
    const float d = x - mean;
    float vs = d * d;
    #pragma unroll
    for (int o = 1; o <= 32; o <<= 1) vs += __shfl_xor(vs, o);
    if ((t & 63) == 0) red2[t >> 6] = vs;
    __syncthreads();
    const float var = (red2[0] + red2[1] + red2[2] + red2[3]) * (1.0f / DIM);
    nrm[t] = d * rsqrtf(var + 1e-5f) * g[t] + bb[t];
    __syncthreads();
    float acc = bq[t];
    for (int c = 0; c < DIM; ++c) acc += nrm[c] * Wq[c * DIM + t];
    Q[k * DIM + t] = acc;
}

// ---- K1: fold scores matrix + transpose. W2T[n][c] (bf16, c contiguous) ----
__global__ void k_fold(const float* __restrict__ Q, const float* __restrict__ Wk,
                       const float* __restrict__ bk, const float* __restrict__ Wv,
                       const float* __restrict__ bv,
                       unsigned short* __restrict__ W2T, float* __restrict__ b2) {
    const int n = blockIdx.x, t = threadIdx.x;
    __shared__ float q[DH];
    if (n < 256) {
        const int h = n >> 6, k = n & 63;
        if (t < DH) q[t] = Q[k * DIM + h * DH + t];
        __syncthreads();
        float acc = 0.f;
        #pragma unroll 8
        for (int d0 = 0; d0 < DH; ++d0) acc += Wk[t * DIM + h * DH + d0] * q[d0];
        W2T[n * 256 + t] = f2bf(acc * 0.125f);
        if (t == 0) {
            float ba = 0.f;
            for (int d0 = 0; d0 < DH; ++d0) ba += bk[h * DH + d0] * q[d0];
            b2[n] = ba * 0.125f;
        }
    } else {
        const int col = n - 256;
        W2T[n * 256 + t] = f2bf(Wv[t * DIM + col]);
        if (t == 0) b2[n] = bv[col];
    }
}

// ======== K2a: PARTIAL-STORE main kernel (no atomics) ========
// Grid 256 = 4b x 64chunks (512 rows = 16 tiles of 32), 1024 thr = 16 waves.
// Identical inner loop to round 7; epilogue stores a private per-block
// partial: num_p[bid][4h][64k][64d] fp32 (64KB) + den_p[bid][4h*64k] (1KB).
// Tests the atomic-storm hypothesis (8.4M device-scope RMWs was the one
// component common to all ~175us rounds).
__global__ __launch_bounds__(1024)
void k_main_part(const float* __restrict__ X, const unsigned short* __restrict__ W2T,
                 const float* __restrict__ b2, float* __restrict__ num_p,
                 float* __restrict__ den_p) {
    extern __shared__ __align__(16) unsigned char smem[];
    const int AB = 32768, VB = 49152, SB = 65536;
    const int tid  = threadIdx.x;
    const int lane = tid & 63;
    const int wid  = tid >> 6;
    const int l15  = lane & 15;
    const int lhi  = lane >> 4;
    const int bid   = blockIdx.x;
    const int b     = bid >> 6;
    const int chunk = bid & 63;
    const float* Xg = X + ((size_t)(b * SEQ + chunk * 512)) * DIM;

    const bool is_score = wid < 8;
    const int h_sc  = wid >> 1;
    const int sh    = wid & 1;
    const int vg    = wid - 8;
    const int h_v   = vg >> 1;
    const int nbase = wid * 32;
    const int hp = wid >> 2;
    const int dq = wid & 3;

    bf16x8 bfr[8][2];
    #pragma unroll
    for (int ks = 0; ks < 8; ++ks)
        #pragma unroll
        for (int ni = 0; ni < 2; ++ni)
            bfr[ks][ni] = *(const bf16x8*)(W2T + (size_t)(nbase + ni * 16 + l15) * 256
                                           + ks * 32 + lhi * 8);
    float bias[2];
    #pragma unroll
    for (int ni = 0; ni < 2; ++ni) bias[ni] = b2[nbase + ni * 16 + l15];

    f32x4 pv[4];
    #pragma unroll
    for (int i = 0; i < 4; ++i) pv[i] = (f32x4){0.f, 0.f, 0.f, 0.f};
    float den_acc[2] = {0.f, 0.f};

    float4 pf[2];
    #pragma unroll
    for (int j = 0; j < 2; ++j) {
        const int f = j * 1024 + tid;
        pf[j] = *(const float4*)(Xg + (f >> 6) * DIM + (f & 63) * 4);
    }
    #pragma unroll
    for (int j = 0; j < 2; ++j) {
        const int f = j * 1024 + tid;
        const int row = f >> 6, c4 = f & 63;
        const int byte = row * 512 + ((c4 * 8) ^ ((row & 7) << 4));
        *(uint2*)(smem + byte) = make_uint2(f2bf2(pf[j].x, pf[j].y), f2bf2(pf[j].z, pf[j].w));
    }
    __syncthreads();

    for (int t = 0; t < 16; ++t) {
        const int tb = t & 1;
        const unsigned char* xbuf = smem + tb * 16384;

        if (t < 15) {
            const float* Xt = Xg + (size_t)(t + 1) * 32 * DIM;
            #pragma unroll
            for (int j = 0; j < 2; ++j) {
                const int f = j * 1024 + tid;
                pf[j] = *(const float4*)(Xt + (f >> 6) * DIM + (f & 63) * 4);
            }
        }

        f32x4 acc[2][2];
        #pragma unroll
        for (int si = 0; si < 2; ++si)
            #pragma unroll
            for (int ni = 0; ni < 2; ++ni)
                acc[si][ni] = (f32x4){bias[ni], bias[ni], bias[ni], bias[ni]};
        #pragma unroll
        for (int ks = 0; ks < 8; ++ks) {
            #pragma unroll
            for (int si = 0; si < 2; ++si) {
                const int row  = si * 16 + l15;
                const int byte = row * 512 + ((ks * 64 + lhi * 16) ^ ((row & 7) << 4));
                const bf16x8 afr = *(const bf16x8*)(xbuf + byte);
                #pragma unroll
                for (int ni = 0; ni < 2; ++ni)
                    acc[si][ni] = __builtin_amdgcn_mfma_f32_16x16x32_bf16(
                        afr, bfr[ks][ni], acc[si][ni], 0, 0, 0);
            }
        }

        if (is_score) {
            #pragma unroll
            for (int si = 0; si < 2; ++si) {
                #pragma unroll
                for (int ni = 0; ni < 2; ++ni)
                    #pragma unroll
                    for (int r = 0; r < 4; ++r)
                        acc[si][ni][r] = __expf(acc[si][ni][r]);
                #pragma unroll
                for (int r = 0; r < 4; ++r) {
                    float p = acc[si][0][r] + acc[si][1][r];
                    p += __shfl_xor(p, 1);
                    p += __shfl_xor(p, 2);
                    p += __shfl_xor(p, 4);
                    p += __shfl_xor(p, 8);
                    if (l15 == 0)
                        *(float*)(smem + SB + (((tb * 4 + h_sc) * 2 + sh) * 32
                                               + si * 16 + lhi * 4 + r) * 4) = p;
                }
            }
        }

        __syncthreads();

        {
            const int hh = is_score ? h_sc : h_v;
            #pragma unroll
            for (int si = 0; si < 2; ++si) {
                const int sbase = SB + ((tb * 4 + hh) * 2) * 128 + (si * 16 + lhi * 4) * 4;
                const f32x4 s0 = *(const f32x4*)(smem + sbase);
                const f32x4 s1 = *(const f32x4*)(smem + sbase + 128);
                float sinv[4];
                #pragma unroll
                for (int r = 0; r < 4; ++r) sinv[r] = 1.0f / (s0[r] + s1[r]);
                if (is_score) {
                    #pragma unroll
                    for (int ni = 0; ni < 2; ++ni) {
                        den_acc[ni] += acc[si][ni][0] * sinv[0] + acc[si][ni][1] * sinv[1]
                                     + acc[si][ni][2] * sinv[2] + acc[si][ni][3] * sinv[3];
                        const int k = sh * 32 + ni * 16 + l15;
                        const int byte = AB + (h_sc * 64 + k) * 64
                                       + ((si * 32 + lhi * 8) ^ (((k >> 1) & 3) << 4));
                        *(uint2*)(smem + byte) = make_uint2(
                            f2bf2(acc[si][ni][0], acc[si][ni][1]),
                            f2bf2(acc[si][ni][2], acc[si][ni][3]));
                    }
                } else {
                    #pragma unroll
                    for (int ni = 0; ni < 2; ++ni) {
                        const int d = vg * 32 + ni * 16 + l15;
                        const int byte = VB + d * 64
                                       + ((si * 32 + lhi * 8) ^ (((d >> 1) & 3) << 4));
                        *(uint2*)(smem + byte) = make_uint2(
                            f2bf2(acc[si][ni][0] * sinv[0], acc[si][ni][1] * sinv[1]),
                            f2bf2(acc[si][ni][2] * sinv[2], acc[si][ni][3] * sinv[3]));
                    }
                }
            }
        }
        if (t < 15) {
            unsigned char* nbuf = smem + (tb ^ 1) * 16384;
            #pragma unroll
            for (int j = 0; j < 2; ++j) {
                const int f = j * 1024 + tid;
                const int row = f >> 6, c4 = f & 63;
                const int byte = row * 512 + ((c4 * 8) ^ ((row & 7) << 4));
                *(uint2*)(nbuf + byte) = make_uint2(f2bf2(pf[j].x, pf[j].y),
                                                    f2bf2(pf[j].z, pf[j].w));
            }
        }

        __syncthreads();

        {
            bf16x8 afr[4];
            #pragma unroll
            for (int mi = 0; mi < 4; ++mi) {
                const int k = mi * 16 + l15;
                afr[mi] = *(const bf16x8*)(smem + AB + (hp * 64 + k) * 64
                                           + ((lhi * 16) ^ (((k >> 1) & 3) << 4)));
            }
            const int d = hp * 64 + dq * 16 + l15;
            const bf16x8 vfr = *(const bf16x8*)(smem + VB + d * 64
                                                + ((lhi * 16) ^ (((d >> 1) & 3) << 4)));
            #pragma unroll
            for (int mi = 0; mi < 4; ++mi)
                pv[mi] = __builtin_amdgcn_mfma_f32_16x16x32_bf16(afr[mi], vfr, pv[mi], 0, 0, 0);
        }
    }

    // ---- epilogue: plain coalesced partial stores, NO atomics ----
    float* np = num_p + (size_t)bid * 16384 + hp * 4096;
    #pragma unroll
    for (int mi = 0; mi < 4; ++mi)
        #pragma unroll
        for (int r = 0; r < 4; ++r)
            np[(mi * 16 + lhi * 4 + r) * 64 + dq * 16 + l15] = pv[mi][r];
    if (is_score) {
        #pragma unroll
        for (int ni = 0; ni < 2; ++ni) {
            float v = den_acc[ni];
            v += __shfl_xor(v, 16);
            v += __shfl_xor(v, 32);
            if (lhi == 0)
                den_p[(size_t)bid * 256 + h_sc * 64 + sh * 32 + ni * 16 + l15] = v;
        }
    }
}

// ======== K2b: ATOMIC fallback (exact round-7 kernel, grid 512) ========
__global__ __launch_bounds__(1024)
void k_main_atom(const float* __restrict__ X, const unsigned short* __restrict__ W2T,
                 const float* __restrict__ b2, float* __restrict__ num_c,
                 float* __restrict__ den_c) {
    extern __shared__ __align__(16) unsigned char smem[];
    const int AB = 32768, VB = 49152, SB = 65536;
    const int tid  = threadIdx.x;
    const int lane = tid & 63;
    const int wid  = tid >> 6;
    const int l15  = lane & 15;
    const int lhi  = lane >> 4;
    const int b     = blockIdx.x >> 7;
    const int chunk = blockIdx.x & 127;
    const int copy  = blockIdx.x & (NCOPY - 1);
    const float* Xg = X + ((size_t)(b * SEQ + chunk * 256)) * DIM;

    const bool is_score = wid < 8;
    const int h_sc  = wid >> 1;
    const int sh    = wid & 1;
    const int vg    = wid - 8;
    const int h_v   = vg >> 1;
    const int nbase = wid * 32;
    const int hp = wid >> 2;
    const int dq = wid & 3;

    bf16x8 bfr[8][2];
    #pragma unroll
    for (int ks = 0; ks < 8; ++ks)
        #pragma unroll
        for (int ni = 0; ni < 2; ++ni)
            bfr[ks][ni] = *(const bf16x8*)(W2T + (size_t)(nbase + ni * 16 + l15) * 256
                                           + ks * 32 + lhi * 8);
    float bias[2];
    #pragma unroll
    for (int ni = 0; ni < 2; ++ni) bias[ni] = b2[nbase + ni * 16 + l15];

    f32x4 pv[4];
    #pragma unroll
    for (int i = 0; i < 4; ++i) pv[i] = (f32x4){0.f, 0.f, 0.f, 0.f};
    float den_acc[2] = {0.f, 0.f};

    float4 pf[2];
    #pragma unroll
    for (int j = 0; j < 2; ++j) {
        const int f = j * 1024 + tid;
        pf[j] = *(const float4*)(Xg + (f >> 6) * DIM + (f & 63) * 4);
    }
    #pragma unroll
    for (int j = 0; j < 2; ++j) {
        const int f = j * 1024 + tid;
        const int row = f >> 6, c4 = f & 63;
        const int byte = row * 512 + ((c4 * 8) ^ ((row & 7) << 4));
        *(uint2*)(smem + byte) = make_uint2(f2bf2(pf[j].x, pf[j].y), f2bf2(pf[j].z, pf[j].w));
    }
    __syncthreads();

    for (int t = 0; t < 8; ++t) {
        const int tb = t & 1;
        const unsigned char* xbuf = smem + tb * 16384;
        if (t < 7) {
            const float* Xt = Xg + (size_t)(t + 1) * 32 * DIM;
            #pragma unroll
            for (int j = 0; j < 2; ++j) {
                const int f = j * 1024 + tid;
                pf[j] = *(const float4*)(Xt + (f >> 6) * DIM + (f & 63) * 4);
            }
        }
        f32x4 acc[2][2];
        #pragma unroll
        for (int si = 0; si < 2; ++si)
            #pragma unroll
            for (int ni = 0; ni < 2; ++ni)
                acc[si][ni] = (f32x4){bias[ni], bias[ni], bias[ni], bias[ni]};
        #pragma unroll
        for (int ks = 0; ks < 8; ++ks) {
            #pragma unroll
            for (int si = 0; si < 2; ++si) {
                const int row  = si * 16 + l15;
                const int byte = row * 512 + ((ks * 64 + lhi * 16) ^ ((row & 7) << 4));
                const bf16x8 afr = *(const bf16x8*)(xbuf + byte);
                #pragma unroll
                for (int ni = 0; ni < 2; ++ni)
                    acc[si][ni] = __builtin_amdgcn_mfma_f32_16x16x32_bf16(
                        afr, bfr[ks][ni], acc[si][ni], 0, 0, 0);
            }
        }
        if (is_score) {
            #pragma unroll
            for (int si = 0; si < 2; ++si) {
                #pragma unroll
                for (int ni = 0; ni < 2; ++ni)
                    #pragma unroll
                    for (int r = 0; r < 4; ++r)
                        acc[si][ni][r] = __expf(acc[si][ni][r]);
                #pragma unroll
                for (int r = 0; r < 4; ++r) {
                    float p = acc[si][0][r] + acc[si][1][r];
                    p += __shfl_xor(p, 1);
                    p += __shfl_xor(p, 2);
                    p += __shfl_xor(p, 4);
                    p += __shfl_xor(p, 8);
                    if (l15 == 0)
                        *(float*)(smem + SB + (((tb * 4 + h_sc) * 2 + sh) * 32
                                               + si * 16 + lhi * 4 + r) * 4) = p;
                }
            }
        }
        __syncthreads();
        {
            const int hh = is_score ? h_sc : h_v;
            #pragma unroll
            for (int si = 0; si < 2; ++si) {
                const int sbase = SB + ((tb * 4 + hh) * 2) * 128 + (si * 16 + lhi * 4) * 4;
                const f32x4 s0 = *(const f32x4*)(smem + sbase);
                const f32x4 s1 = *(const f32x4*)(smem + sbase + 128);
                float sinv[4];
                #pragma unroll
                for (int r = 0; r < 4; ++r) sinv[r] = 1.0f / (s0[r] + s1[r]);
                if (is_score) {
                    #pragma unroll
                    for (int ni = 0; ni < 2; ++ni) {
                        den_acc[ni] += acc[si][ni][0] * sinv[0] + acc[si][ni][1] * sinv[1]
                                     + acc[si][ni][2] * sinv[2] + acc[si][ni][3] * sinv[3];
                        const int k = sh * 32 + ni * 16 + l15;
                        const int byte = AB + (h_sc * 64 + k) * 64
                                       + ((si * 32 + lhi * 8) ^ (((k >> 1) & 3) << 4));
                        *(uint2*)(smem + byte) = make_uint2(
                            f2bf2(acc[si][ni][0], acc[si][ni][1]),
                            f2bf2(acc[si][ni][2], acc[si][ni][3]));
                    }
                } else {
                    #pragma unroll
                    for (int ni = 0; ni < 2; ++ni) {
                        const int d = vg * 32 + ni * 16 + l15;
                        const int byte = VB + d * 64
                                       + ((si * 32 + lhi * 8) ^ (((d >> 1) & 3) << 4));
                        *(uint2*)(smem + byte) = make_uint2(
                            f2bf2(acc[si][ni][0] * sinv[0], acc[si][ni][1] * sinv[1]),
                            f2bf2(acc[si][ni][2] * sinv[2], acc[si][ni][3] * sinv[3]));
                    }
                }
            }
        }
        if (t < 7) {
            unsigned char* nbuf = smem + (tb ^ 1) * 16384;
            #pragma unroll
            for (int j = 0; j < 2; ++j) {
                const int f = j * 1024 + tid;
                const int row = f >> 6, c4 = f & 63;
                const int byte = row * 512 + ((c4 * 8) ^ ((row & 7) << 4));
                *(uint2*)(nbuf + byte) = make_uint2(f2bf2(pf[j].x, pf[j].y),
                                                    f2bf2(pf[j].z, pf[j].w));
            }
        }
        __syncthreads();
        {
            bf16x8 afr[4];
            #pragma unroll
            for (int mi = 0; mi < 4; ++mi) {
                const int k = mi * 16 + l15;
                afr[mi] = *(const bf16x8*)(smem + AB + (hp * 64 + k) * 64
                                           + ((lhi * 16) ^ (((k >> 1) & 3) << 4)));
            }
            const int d = hp * 64 + dq * 16 + l15;
            const bf16x8 vfr = *(const bf16x8*)(smem + VB + d * 64
                                                + ((lhi * 16) ^ (((d >> 1) & 3) << 4)));
            #pragma unroll
            for (int mi = 0; mi < 4; ++mi)
                pv[mi] = __builtin_amdgcn_mfma_f32_16x16x32_bf16(afr[mi], vfr, pv[mi], 0, 0, 0);
        }
    }

    if (is_score) {
        #pragma unroll
        for (int ni = 0; ni < 2; ++ni) {
            float v = den_acc[ni];
            v += __shfl_xor(v, 16);
            v += __shfl_xor(v, 32);
            if (lhi == 0)
                atomicAdd(&den_c[((copy * 4 + b) * NH + h_sc) * NKS
                                 + sh * 32 + ni * 16 + l15], v);
        }
    }
    #pragma unroll
    for (int mi = 0; mi < 4; ++mi)
        #pragma unroll
        for (int r = 0; r < 4; ++r) {
            const int k = mi * 16 + lhi * 4 + r;
            const int d = dq * 16 + l15;
            atomicAdd(&num_c[(((size_t)(copy * 4 + b) * NH + hp) * NKS + k) * DH + d],
                      pv[mi][r]);
        }
}

// ---- K3a: reduce 64 chunk-partials; LN ----
__global__ void k_final_part(const float* __restrict__ num_p, const float* __restrict__ den_p,
                             const float* __restrict__ ga, const float* __restrict__ gb,
                             float* __restrict__ out) {
    __shared__ float red1[4], red2[4];
    const int b = blockIdx.x >> 6, k = blockIdx.x & 63;
    const int t = threadIdx.x;
    const int h = t >> 6, dd = t & 63;
    float nsum = 0.f, dsum = 0.f;
    #pragma unroll 8
    for (int c = 0; c < 64; ++c) {
        const size_t bid = (size_t)(b * 64 + c);
        nsum += num_p[bid * 16384 + h * 4096 + k * 64 + dd];
        dsum += den_p[bid * 256 + h * 64 + k];
    }
    const float val = nsum / (dsum + 1e-20f);
    float s = val;
    #pragma unroll
    for (int o = 1; o <= 32; o <<= 1) s += __shfl_xor(s, o);
    if ((t & 63) == 0) red1[t >> 6] = s;
    __syncthreads();
    const float mean = (red1[0] + red1[1] + red1[2] + red1[3]) * (1.0f / DIM);
    const float d = val - mean;
    float vs = d * d;
    #pragma unroll
    for (int o = 1; o <= 32; o <<= 1) vs += __shfl_xor(vs, o);
    if ((t & 63) == 0) red2[t >> 6] = vs;
    __syncthreads();
    const float var = (red2[0] + red2[1] + red2[2] + red2[3]) * (1.0f / DIM);
    out[(size_t)(b * NKS + k) * DIM + t] = d * rsqrtf(var + 1e-5f) * ga[t] + gb[t];
}

// ---- K3b: fallback final (round-7) ----
__global__ void k_final_atom(const float* __restrict__ num_c, const float* __restrict__ den_c,
                             const float* __restrict__ ga, const float* __restrict__ gb,
                             float* __restrict__ out) {
    __shared__ float red1[4], red2[4];
    const int b = blockIdx.x >> 6, k = blockIdx.x & 63;
    const int t = threadIdx.x;
    const int h = t >> 6, dd = t & 63;
    float nsum = 0.f, dsum = 0.f;
    #pragma unroll
    for (int c = 0; c < NCOPY; ++c) {
        nsum += num_c[(((size_t)(c * 4 + b) * NH + h) * NKS + k) * DH + dd];
        dsum += den_c[((c * 4 + b) * NH + h) * NKS + k];
    }
    const float val = nsum / (dsum + 1e-20f);
    float s = val;
    #pragma unroll
    for (int o = 1; o <= 32; o <<= 1) s += __shfl_xor(s, o);
    if ((t & 63) == 0) red1[t >> 6] = s;
    __syncthreads();
    const float mean = (red1[0] + red1[1] + red1[2] + red1[3]) * (1.0f / DIM);
    const float d = val - mean;
    float vs = d * d;
    #pragma unroll
    for (int o = 1; o <= 32; o <<= 1) vs += __shfl_xor(vs, o);
    if ((t & 63) == 0) red2[t >> 6] = vs;
    __syncthreads();
    const float var = (red2[0] + red2[1] + red2[2] + red2[3]) * (1.0f / DIM);
    out[(size_t)(b * NKS + k) * DIM + t] = d * rsqrtf(var + 1e-5f) * ga[t] + gb[t];
}

extern "C" void kernel_launch(void* const* d_in, const int* in_sizes, int n_in,
                              void* d_out, int out_size, void* d_ws, size_t ws_size,
                              hipStream_t stream) {
    const float* X      = (const float*)d_in[0];
    const float* mu     = (const float*)d_in[1];
    const float* ln_s_g = (const float*)d_in[2];
    const float* ln_s_b = (const float*)d_in[3];
    const float* Wq     = (const float*)d_in[4];
    const float* bq     = (const float*)d_in[5];
    const float* Wk     = (const float*)d_in[6];
    const float* bk     = (const float*)d_in[7];
    const float* Wv     = (const float*)d_in[8];
    const float* bv     = (const float*)d_in[9];
    const float* ln_a_g = (const float*)d_in[10];
    const float* ln_a_b = (const float*)d_in[11];
    float* out = (float*)d_out;

    char* ws = (char*)d_ws;
    float*          Q     = (float*)(ws);                    //  65536 B
    unsigned short* W2T   = (unsigned short*)(ws + 65536);   // 262144 B
    float*          b2    = (float*)(ws + 327680);           //   2048 B

    hipFuncSetAttribute((const void*)k_main_part,
                        hipFuncAttributeMaxDynamicSharedMemorySize, 67584);
    hipFuncSetAttribute((const void*)k_main_atom,
                        hipFuncAttributeMaxDynamicSharedMemorySize, 67584);
    hipLaunchKernelGGL(k_q,    dim3(64),  dim3(256), 0, stream, mu, ln_s_g, ln_s_b, Wq, bq, Q);
    hipLaunchKernelGGL(k_fold, dim3(512), dim3(256), 0, stream, Q, Wk, bk, Wv, bv, W2T, b2);

    const size_t need = 329728 + (size_t)256 * 16384 * 4 + (size_t)256 * 256 * 4;
    if (ws_size >= need) {
        // -------- partial-store path (no atomics) --------
        float* num_p = (float*)(ws + 329728);                  // 16 MiB
        float* den_p = (float*)(ws + 329728 + 16777216);       // 256 KiB
        hipLaunchKernelGGL(k_main_part, dim3(256), dim3(1024), 67584, stream,
                           X, W2T, b2, num_p, den_p);
        hipLaunchKernelGGL(k_final_part, dim3(256), dim3(256), 0, stream,
                           num_p, den_p, ln_a_g, ln_a_b, out);
    } else {
        // -------- atomic fallback (round-7 behavior) --------
        float* num_c = (float*)(ws + 329728);                  // 2 MiB
        float* den_c = (float*)(ws + 2426880);                 // 32 KiB
        hipMemsetAsync(ws + 329728, 0, 2097152 + 32768, stream);
        hipLaunchKernelGGL(k_main_atom, dim3(512), dim3(1024), 67584, stream,
                           X, W2T, b2, num_c, den_c);
        hipLaunchKernelGGL(k_final_atom, dim3(256), dim3(256), 0, stream,
                           num_c, den_c, ln_a_g, ln_a_b, out);
    }
}